// Round 1
// 907.049 us; speedup vs baseline: 1.0135x; 1.0135x over previous
//
#include <hip/hip_runtime.h>

// Scattering_v3_tau: B=500000, C=30, NCON=8, NCC=3, NH=7
// Round 3: cut VALU issue count (kernel is VALU-issue-bound: VALUBusy~104%, HBM 25%).
//  - cc features folded into per-c layer-1 biases (prep kernel)
//  - diffuse MLP via v_dot2_f32_f16 (2 FMA/instr, f32 accumulate, f16 RNE activations)
//  - direct MLP kept full f32 (features scale with 1/(mu+eps) up to ~1e7 -> precision-critical)
//  - softmax via exp2 with log2(e) folded; outputs packed with v_cvt_pk_bf16_f32
//  - dtype detector merged into prep kernel (64-lane ballot, parallel)

#define B_SZ 500000
#define C_SZ 30
#define BC   (B_SZ * C_SZ)
#define EPSF 1e-7f
#define LOG2E 1.4426950408889634f

#if __has_builtin(__builtin_amdgcn_fdot2)
#define HAVE_FDOT2 1
#else
#define HAVE_FDOT2 0
#endif

typedef __fp16 h2 __attribute__((ext_vector_type(2)));

// ws layout (float indices)
enum {
    WD1C  = 0,     // [7][6]  direct L1 weights, feature order [t0r,t1r,t5r,t2r,s1r,mu]
    WDH   = 42,    // [5][7][7]
    BDH   = 287,   // [5][7]
    WDO   = 322,   // [3][7]  (x LOG2E)
    BDO   = 343,   // [3]     (x LOG2E)
    BEFFD = 352,   // [30][8] f32, 16B aligned
    BEFFF = 592,   // [30][8] f32
    VF16  = 832,   // [7][4]  h2 pairs, natural-t order
    WFH16 = 860,   // [5*7][4] h2 pairs
    WFO16 = 1000,  // [3][4]  h2 pairs (unscaled)
    BFO   = 1012,  // [3]     (unscaled)
    BFH   = 1015,  // [5][7]
    VFF   = 1056,  // [7][8]  f32 diffuse L1, natural-t order (fallback / f32 mode)
    WFHF  = 1112,  // [5][7][7]
    WFOF  = 1357,  // [3][7]  (unscaled)
    WS_FLOATS = 1378
};
#define FLAG_BYTE_OFF 6144

__device__ __forceinline__ float bf2f(unsigned short u) {
    union { unsigned int i; float f; } v;
    v.i = ((unsigned int)u) << 16;
    return v.f;
}

__device__ __forceinline__ float ex2(float x) {
    float r;
    asm("v_exp_f32 %0, %1" : "=v"(r) : "v"(x));
    return r;
}

__device__ __forceinline__ unsigned int pk_bf16(float lo, float hi) {
    unsigned int r;
    asm("v_cvt_pk_bf16_f32 %0, %1, %2" : "=v"(r) : "v"(lo), "v"(hi));
    return r;
}

#if HAVE_FDOT2
__device__ __forceinline__ h2 uash2(unsigned int u) {
    union { unsigned int u; h2 h; } v; v.u = u; return v.h;
}
#endif

struct P12 { const void* p[12]; };
// seg order: 0:Wd1(7x9) 1:bd1(7) 2:Wdh(5x7x7) 3:bdh(5x7) 4:Wdo(3x7) 5:bdo(3)
//            6:Wf1(7x8) 7:bf1(7) 8:Wfh(5x7x7) 9:bfh(5x7) 10:Wfo(3x7) 11:bfo(3)

__global__ void prep(P12 ptrs, const unsigned int* __restrict__ tau_raw,
                     float* __restrict__ ws, int* __restrict__ flagp)
{
    __shared__ int sflag;
    int tid = threadIdx.x;
    // dtype detect: bit15 of raw words is 0 for packed non-negative bf16 pairs,
    // ~50%-random for f32 mantissas. 64 words -> P(miss) ~ 2^-64.
    if (tid < 64) {
        unsigned long long m = __ballot((tau_raw[tid] & 0x8000u) != 0u);
        if (tid == 0) { sflag = (m != 0ull) ? 1 : 0; *flagp = sflag; }
    }
    __syncthreads();
    const int f32m = sflag;

    auto rd = [&](int seg, int idx) -> float {
        if (f32m) return ((const float*)ptrs.p[seg])[idx];
        return bf2f(((const unsigned short*)ptrs.p[seg])[idx]);
    };
    auto ccf = [&](int c, int k) -> float {
        const float C1 = 1.0f / (0.25f * sqrtf(6.28f));
        float ii = (float)c * (1.0f / 29.0f);
        float jj = (float)k * 0.5f;
        float d = (ii - jj) * 4.0f;
        return C1 * expf(-0.5f * d * d);
    };
    auto pk = [&](float a, float b) -> unsigned int {
        union { h2 h; unsigned int u; } v;
        v.h.x = (__fp16)a; v.h.y = (__fp16)b;
        return v.u;
    };
    unsigned int* wsu = (unsigned int*)ws;

    // direct L1 compact: cols 0..5 of Wd1
    for (int i = tid; i < 42; i += 256) { int j = i / 6, k = i % 6; ws[WD1C + i] = rd(0, j * 9 + k); }
    for (int i = tid; i < 245; i += 256) ws[WDH + i] = rd(2, i);
    for (int i = tid; i < 35;  i += 256) ws[BDH + i] = rd(3, i);
    for (int i = tid; i < 21;  i += 256) ws[WDO + i] = rd(4, i) * LOG2E;
    for (int i = tid; i < 3;   i += 256) ws[BDO + i] = rd(5, i) * LOG2E;
    // beff_d[c][j] = bd1[j] + sum_k Wd1[j,6+k]*cc[c][k]
    for (int i = tid; i < 240; i += 256) {
        int c = i / 8, j = i % 8; float v = 0.f;
        if (j < 7) v = rd(1, j) + rd(0, j * 9 + 6) * ccf(c, 0)
                               + rd(0, j * 9 + 7) * ccf(c, 1)
                               + rd(0, j * 9 + 8) * ccf(c, 2);
        ws[BEFFD + i] = v;
    }
    // beff_f[c][j] = bf1[j] + sum_k Wf1[j,5+k]*cc[c][k]
    for (int i = tid; i < 240; i += 256) {
        int c = i / 8, j = i % 8; float v = 0.f;
        if (j < 7) v = rd(7, j) + rd(6, j * 8 + 5) * ccf(c, 0)
                               + rd(6, j * 8 + 6) * ccf(c, 1)
                               + rd(6, j * 8 + 7) * ccf(c, 2);
        ws[BEFFF + i] = v;
    }
    // diffuse L1 f16 pairs, natural t order: coeffs for (t0..t7) = cols (0,1,3,4,4,2,4,4)
    for (int i = tid; i < 28; i += 256) {
        int j = i / 4, p = i % 4; float lo, hi;
        if      (p == 0) { lo = rd(6, j * 8 + 0); hi = rd(6, j * 8 + 1); }
        else if (p == 1) { lo = rd(6, j * 8 + 3); hi = rd(6, j * 8 + 4); }
        else if (p == 2) { lo = rd(6, j * 8 + 4); hi = rd(6, j * 8 + 2); }
        else             { lo = rd(6, j * 8 + 4); hi = rd(6, j * 8 + 4); }
        wsu[VF16 + i] = pk(lo, hi);
    }
    // diffuse hidden f16 pairs
    for (int i = tid; i < 140; i += 256) {
        int lj = i / 4, p = i % 4; float lo, hi;
        if (p < 3) { lo = rd(8, lj * 7 + 2 * p); hi = rd(8, lj * 7 + 2 * p + 1); }
        else       { lo = rd(8, lj * 7 + 6);     hi = 0.f; }
        wsu[WFH16 + i] = pk(lo, hi);
    }
    // diffuse out f16 pairs (unscaled; LOG2E applied to logits at runtime)
    for (int i = tid; i < 12; i += 256) {
        int j = i / 4, p = i % 4; float lo, hi;
        if (p < 3) { lo = rd(10, j * 7 + 2 * p); hi = rd(10, j * 7 + 2 * p + 1); }
        else       { lo = rd(10, j * 7 + 6);     hi = 0.f; }
        wsu[WFO16 + i] = pk(lo, hi);
    }
    for (int i = tid; i < 3;   i += 256) ws[BFO + i] = rd(11, i);
    for (int i = tid; i < 35;  i += 256) ws[BFH + i] = rd(9, i);
    // f32 diffuse fallback (natural-t V-form)
    for (int i = tid; i < 56; i += 256) {
        int j = i / 8, k = i % 8;
        const int cols[8] = {0, 1, 3, 4, 4, 2, 4, 4};
        ws[VFF + i] = rd(6, j * 8 + cols[k]);
    }
    for (int i = tid; i < 245; i += 256) ws[WFHF + i] = rd(8, i);
    for (int i = tid; i < 21;  i += 256) ws[WFOF + i] = rd(10, i);
}

__global__ __launch_bounds__(256) void scatter_main(
    const void* __restrict__ tau_p,    // (B,C,8) bf16 or f32
    const void* __restrict__ mu_dir_p, // (B,1)
    const void* __restrict__ mu_dif_p, // (B,1)
    const float* __restrict__ ws,
    const int* __restrict__ flag,      // 1 = f32, 0 = bf16
    void* __restrict__ out_p)          // out: [BC | BC | 3BC | 3BC]
{
    int e = blockIdx.x * 256 + threadIdx.x;
    if (e >= BC) return;
    int b = e / C_SZ;
    int c = e - b * C_SZ;

    int is_f32 = *flag;  // uniform -> scalar branch

    float t0, t1, t2, t3, t4, t5, t6, t7, mu_d, mu_f;
    if (is_f32) {
        const float4* tf = (const float4*)tau_p;
        float4 a = tf[2 * e];
        float4 bq = tf[2 * e + 1];
        t0 = a.x; t1 = a.y; t2 = a.z; t3 = a.w;
        t4 = bq.x; t5 = bq.y; t6 = bq.z; t7 = bq.w;
        mu_d = ((const float*)mu_dir_p)[b];
        mu_f = ((const float*)mu_dif_p)[b];
    } else {
        uint4 t = ((const uint4*)tau_p)[e];
        t0 = bf2f((unsigned short)(t.x & 0xffffu));
        t1 = bf2f((unsigned short)(t.x >> 16));
        t2 = bf2f((unsigned short)(t.y & 0xffffu));
        t3 = bf2f((unsigned short)(t.y >> 16));
        t4 = bf2f((unsigned short)(t.z & 0xffffu));
        t5 = bf2f((unsigned short)(t.z >> 16));
        t6 = bf2f((unsigned short)(t.w & 0xffffu));
        t7 = bf2f((unsigned short)(t.w >> 16));
        mu_d = bf2f(((const unsigned short*)mu_dir_p)[b]);
        mu_f = bf2f(((const unsigned short*)mu_dif_p)[b]);
    }

    float rcp_d = __builtin_amdgcn_rcpf(mu_d + EPSF);
    float rcp_f = __builtin_amdgcn_rcpf(mu_f + EPSF);

    float tau_total = ((t0 + t1) + (t2 + t3)) + ((t4 + t5) + (t6 + t7));
    float ttl = tau_total * LOG2E;
    float t_direct  = ex2(-ttl * rcp_d);
    float t_diffuse = ex2(-ttl * rcp_f);
    float s1 = (t3 + t4) + (t6 + t7);

    // per-c effective biases (cc folded), L1-resident vector loads
    const float4* bdv = (const float4*)(ws + BEFFD);
    float4 bda = bdv[2 * c], bdb = bdv[2 * c + 1];
    const float4* bfv = (const float4*)(ws + BEFFF);
    float4 bfa = bfv[2 * c], bfb = bfv[2 * c + 1];
    float beffd[8] = {bda.x, bda.y, bda.z, bda.w, bdb.x, bdb.y, bdb.z, bdb.w};
    float befff[8] = {bfa.x, bfa.y, bfa.z, bfa.w, bfb.x, bfb.y, bfb.z, bfb.w};

    // ---------------- direct MLP: full f32 (precision-critical path) ----------------
    float xd[6] = {t0 * rcp_d, t1 * rcp_d, t5 * rcp_d, t2 * rcp_d, s1 * rcp_d, mu_d};
    float h[7];
#pragma unroll
    for (int j = 0; j < 7; ++j) {
        float a = beffd[j];
#pragma unroll
        for (int i = 0; i < 6; ++i) a = fmaf(xd[i], ws[WD1C + j * 6 + i], a);
        h[j] = fmaxf(a, 0.0f);
    }
#pragma unroll
    for (int l = 0; l < 5; ++l) {
        float hn[7];
#pragma unroll
        for (int j = 0; j < 7; ++j) {
            float a = ws[BDH + l * 7 + j];
#pragma unroll
            for (int i = 0; i < 7; ++i) a = fmaf(h[i], ws[WDH + l * 49 + j * 7 + i], a);
            hn[j] = fmaxf(a, 0.0f);
        }
#pragma unroll
        for (int j = 0; j < 7; ++j) h[j] = hn[j];
    }
    float od[3];
#pragma unroll
    for (int k = 0; k < 3; ++k) {
        float a = ws[BDO + k];  // pre-scaled by LOG2E
#pragma unroll
        for (int i = 0; i < 7; ++i) a = fmaf(h[i], ws[WDO + k * 7 + i], a);
        od[k] = a;
    }
    float md = fmaxf(fmaxf(od[0], od[1]), od[2]);
    float d0 = ex2(od[0] - md), d1 = ex2(od[1] - md), d2 = ex2(od[2] - md);
    float rd_ = __builtin_amdgcn_rcpf(d0 + d1 + d2);
    d0 *= rd_; d1 *= rd_; d2 *= rd_;

    // ---------------- diffuse MLP ----------------
    float lf0, lf1, lf2;
#if HAVE_FDOT2
    if (!is_f32) {
        const unsigned int* wsu = (const unsigned int*)ws;
        h2 xp0 = __builtin_amdgcn_cvt_pkrtz(t0, t1);   // bf16->f16 exact
        h2 xp1 = __builtin_amdgcn_cvt_pkrtz(t2, t3);
        h2 xp2 = __builtin_amdgcn_cvt_pkrtz(t4, t5);
        h2 xp3 = __builtin_amdgcn_cvt_pkrtz(t6, t7);
        float hf[7];
#pragma unroll
        for (int j = 0; j < 7; ++j) {
            float a = befff[j];
            a = __builtin_amdgcn_fdot2(xp0, uash2(wsu[VF16 + j * 4 + 0]), a, false);
            a = __builtin_amdgcn_fdot2(xp1, uash2(wsu[VF16 + j * 4 + 1]), a, false);
            a = __builtin_amdgcn_fdot2(xp2, uash2(wsu[VF16 + j * 4 + 2]), a, false);
            a = __builtin_amdgcn_fdot2(xp3, uash2(wsu[VF16 + j * 4 + 3]), a, false);
            hf[j] = fmaxf(a, 0.0f);
        }
#pragma unroll
        for (int l = 0; l < 5; ++l) {
            h2 hp0, hp1, hp2, hp3;  // RNE pack of activations
            hp0.x = (__fp16)hf[0]; hp0.y = (__fp16)hf[1];
            hp1.x = (__fp16)hf[2]; hp1.y = (__fp16)hf[3];
            hp2.x = (__fp16)hf[4]; hp2.y = (__fp16)hf[5];
            hp3.x = (__fp16)hf[6]; hp3.y = (__fp16)0.0f;
            float hn[7];
#pragma unroll
            for (int j = 0; j < 7; ++j) {
                int wb = WFH16 + (l * 7 + j) * 4;
                float a = ws[BFH + l * 7 + j];
                a = __builtin_amdgcn_fdot2(hp0, uash2(wsu[wb + 0]), a, false);
                a = __builtin_amdgcn_fdot2(hp1, uash2(wsu[wb + 1]), a, false);
                a = __builtin_amdgcn_fdot2(hp2, uash2(wsu[wb + 2]), a, false);
                a = __builtin_amdgcn_fdot2(hp3, uash2(wsu[wb + 3]), a, false);
                hn[j] = fmaxf(a, 0.0f);
            }
#pragma unroll
            for (int j = 0; j < 7; ++j) hf[j] = hn[j];
        }
        h2 op0, op1, op2, op3;
        op0.x = (__fp16)hf[0]; op0.y = (__fp16)hf[1];
        op1.x = (__fp16)hf[2]; op1.y = (__fp16)hf[3];
        op2.x = (__fp16)hf[4]; op2.y = (__fp16)hf[5];
        op3.x = (__fp16)hf[6]; op3.y = (__fp16)0.0f;
        float lo[3];
#pragma unroll
        for (int k = 0; k < 3; ++k) {
            float a = ws[BFO + k];
            a = __builtin_amdgcn_fdot2(op0, uash2(wsu[WFO16 + k * 4 + 0]), a, false);
            a = __builtin_amdgcn_fdot2(op1, uash2(wsu[WFO16 + k * 4 + 1]), a, false);
            a = __builtin_amdgcn_fdot2(op2, uash2(wsu[WFO16 + k * 4 + 2]), a, false);
            a = __builtin_amdgcn_fdot2(op3, uash2(wsu[WFO16 + k * 4 + 3]), a, false);
            lo[k] = a * LOG2E;
        }
        lf0 = lo[0]; lf1 = lo[1]; lf2 = lo[2];
    } else
#endif
    {
        // f32 V-form (f32-input mode, or fdot2 unavailable)
        float tarr[8] = {t0, t1, t2, t3, t4, t5, t6, t7};
        float hf[7];
#pragma unroll
        for (int j = 0; j < 7; ++j) {
            float a = befff[j];
#pragma unroll
            for (int i = 0; i < 8; ++i) a = fmaf(tarr[i], ws[VFF + j * 8 + i], a);
            hf[j] = fmaxf(a, 0.0f);
        }
#pragma unroll
        for (int l = 0; l < 5; ++l) {
            float hn[7];
#pragma unroll
            for (int j = 0; j < 7; ++j) {
                float a = ws[BFH + l * 7 + j];
#pragma unroll
                for (int i = 0; i < 7; ++i) a = fmaf(hf[i], ws[WFHF + l * 49 + j * 7 + i], a);
                hn[j] = fmaxf(a, 0.0f);
            }
#pragma unroll
            for (int j = 0; j < 7; ++j) hf[j] = hn[j];
        }
        float lo[3];
#pragma unroll
        for (int k = 0; k < 3; ++k) {
            float a = ws[BFO + k];
#pragma unroll
            for (int i = 0; i < 7; ++i) a = fmaf(hf[i], ws[WFOF + k * 7 + i], a);
            lo[k] = a * LOG2E;
        }
        lf0 = lo[0]; lf1 = lo[1]; lf2 = lo[2];
    }
    float mf = fmaxf(fmaxf(lf0, lf1), lf2);
    float f0 = ex2(lf0 - mf), f1 = ex2(lf1 - mf), f2 = ex2(lf2 - mf);
    float rf = __builtin_amdgcn_rcpf(f0 + f1 + f2);
    f0 *= rf; f1 *= rf; f2 *= rf;

    // ---------------- stores ----------------
    int odb = 2 * BC + 3 * e;
    int ofb = 5 * BC + 3 * e;
    if (is_f32) {
        float* out = (float*)out_p;
        out[e] = t_direct;
        out[BC + e] = t_diffuse;
        out[odb + 0] = d0; out[odb + 1] = d1; out[odb + 2] = d2;
        out[ofb + 0] = f0; out[ofb + 1] = f1; out[ofb + 2] = f2;
    } else {
        unsigned short* out = (unsigned short*)out_p;
        unsigned int P1 = pk_bf16(t_direct, t_diffuse);
        unsigned int P2 = pk_bf16(d0, d1);
        unsigned int P3 = pk_bf16(d2, f0);
        unsigned int P4 = pk_bf16(f1, f2);
        out[e]       = (unsigned short)P1;
        out[BC + e]  = (unsigned short)(P1 >> 16);
        out[odb + 0] = (unsigned short)P2;
        out[odb + 1] = (unsigned short)(P2 >> 16);
        out[odb + 2] = (unsigned short)P3;
        out[ofb + 0] = (unsigned short)(P3 >> 16);
        out[ofb + 1] = (unsigned short)P4;
        out[ofb + 2] = (unsigned short)(P4 >> 16);
    }
}

extern "C" void kernel_launch(void* const* d_in, const int* in_sizes, int n_in,
                              void* d_out, int out_size, void* d_ws, size_t ws_size,
                              hipStream_t stream) {
    float* ws = (float*)d_ws;
    int* flag = (int*)((char*)d_ws + FLAG_BYTE_OFF);

    P12 p;
    for (int i = 0; i < 12; ++i) p.p[i] = d_in[3 + i];
    prep<<<1, 256, 0, stream>>>(p, (const unsigned int*)d_in[0], ws, flag);

    int nblk = (BC + 255) / 256;
    scatter_main<<<nblk, 256, 0, stream>>>(
        d_in[0], d_in[1], d_in[2], ws, flag, d_out);
}

// Round 2
// 839.742 us; speedup vs baseline: 1.0947x; 1.0802x over previous
//
#include <hip/hip_runtime.h>

// Scattering_v3_tau: B=500000, C=30, NCON=8, NCC=3, NH=7
// Round 4:
//  - both MLPs in packed f32 (v_pk_fma_f32 via float2 elementwise builtins):
//    2 IEEE f32 FMA per VALU slot, bit-identical accumulation order per neuron.
//    Output neurons processed in pairs (4 pairs, zero-padded 8th neuron).
//  - LDS-staged coalesced output stores: 8 sub-dword ushort stores (measured 2x
//    HBM write amplification: WRITE_SIZE=480MB for a 240MB bf16 output) replaced
//    by 8 ds_write_u16 + 1 global_store_dwordx4 per thread.
//  - cc folded into per-c layer-1 biases; LOG2E folded into both output layers;
//    softmax via v_exp_f32 (exp2); outputs packed with v_cvt_pk_bf16_f32.
//  - dtype-adaptive (bf16/f32) as before; compute path is identical f32 math in
//    both modes now (packed f32 == scalar f32 numerics).

#define B_SZ 500000
#define C_SZ 30
#define BC   (B_SZ * C_SZ)
#define EPSF 1e-7f
#define LOG2E 1.4426950408889634f

typedef float f2 __attribute__((ext_vector_type(2)));

// ws layout (float indices; all segment starts even -> 8B aligned for f2)
enum {
    WD1P  = 0,     // [6][4][2]   direct L1, pairs of neurons, feature order [t0r,t1r,t5r,t2r,s1r,mu]
    WDHP  = 48,    // [5][7][4][2]
    WDOP  = 328,   // [7][2][2]   (x LOG2E)
    BDOP  = 356,   // [2][2]      (x LOG2E)  {b0,b1},{b2,0}
    BEFFD = 360,   // [30][8]     cc-folded L1 biases, direct (slot7 = 0)
    BEFFF = 600,   // [30][8]     diffuse
    WF1P  = 840,   // [8][4][2]   diffuse L1, natural-t order
    WFHP  = 904,   // [5][7][4][2]
    WFOP  = 1184,  // [7][2][2]   (x LOG2E)
    BFOP  = 1212,  // [2][2]      (x LOG2E)
    BDHP  = 1216,  // [5][4][2]   hidden bias pairs, direct
    BFHP  = 1256,  // [5][4][2]   diffuse
    WS_FLOATS = 1296
};
#define FLAG_BYTE_OFF 6144

__device__ __forceinline__ float bf2f(unsigned short u) {
    union { unsigned int i; float f; } v;
    v.i = ((unsigned int)u) << 16;
    return v.f;
}

__device__ __forceinline__ unsigned short f2bf(float f) {
    union { float f; unsigned int i; } v;
    v.f = f;
    unsigned int u = v.i;
    unsigned int r = u + 0x7fffu + ((u >> 16) & 1u);  // RNE
    return (unsigned short)(r >> 16);
}

__device__ __forceinline__ float ex2(float x) {
    float r;
    asm("v_exp_f32 %0, %1" : "=v"(r) : "v"(x));
    return r;
}

__device__ __forceinline__ unsigned int pk_bf16(float lo, float hi) {
    unsigned int r;
    asm("v_cvt_pk_bf16_f32 %0, %1, %2" : "=v"(r) : "v"(lo), "v"(hi));
    return r;
}

__device__ __forceinline__ f2 pkfma(f2 a, f2 b, f2 c) {
#if __has_builtin(__builtin_elementwise_fma)
    return __builtin_elementwise_fma(a, b, c);
#else
    f2 r; r.x = fmaf(a.x, b.x, c.x); r.y = fmaf(a.y, b.y, c.y); return r;
#endif
}

__device__ __forceinline__ f2 pkmax0(f2 a) {
    f2 z = {0.0f, 0.0f};
#if __has_builtin(__builtin_elementwise_max)
    return __builtin_elementwise_max(a, z);
#else
    f2 r; r.x = fmaxf(a.x, 0.f); r.y = fmaxf(a.y, 0.f); return r;
#endif
}

// splat one half of a pair (hl is compile-time constant after unrolling)
__device__ __forceinline__ f2 bc(f2 v, int hl) {
    return hl ? __builtin_shufflevector(v, v, 1, 1)
              : __builtin_shufflevector(v, v, 0, 0);
}

// packed-f32 MLP: NIN inputs (as ceil(NIN/2) f2 pairs), 5 hidden layers of 7,
// 3 outputs. Per-neuron accumulation order identical to the scalar version.
template <int NIN, int W1, int WH, int BH, int WO, int BO>
__device__ __forceinline__ void mlp_pk(const float* __restrict__ ws,
                                       const f2* __restrict__ x2,
                                       const f2* __restrict__ be,
                                       float* __restrict__ o) {
    const f2* w1 = (const f2*)(ws + W1);
    f2 h[4] = {be[0], be[1], be[2], be[3]};
#pragma unroll
    for (int i = 0; i < NIN; ++i) {
        f2 xx = bc(x2[i >> 1], i & 1);
#pragma unroll
        for (int p = 0; p < 4; ++p) h[p] = pkfma(xx, w1[i * 4 + p], h[p]);
    }
#pragma unroll
    for (int p = 0; p < 4; ++p) h[p] = pkmax0(h[p]);

    const f2* wh = (const f2*)(ws + WH);
    const f2* bh = (const f2*)(ws + BH);
#pragma unroll
    for (int l = 0; l < 5; ++l) {
        f2 hn[4];
#pragma unroll
        for (int p = 0; p < 4; ++p) hn[p] = bh[l * 4 + p];
#pragma unroll
        for (int i = 0; i < 7; ++i) {
            f2 xx = bc(h[i >> 1], i & 1);
#pragma unroll
            for (int p = 0; p < 4; ++p) hn[p] = pkfma(xx, wh[(l * 7 + i) * 4 + p], hn[p]);
        }
#pragma unroll
        for (int p = 0; p < 4; ++p) h[p] = pkmax0(hn[p]);
    }

    const f2* wo = (const f2*)(ws + WO);
    const f2* bo = (const f2*)(ws + BO);
    f2 oA = bo[0], oB = bo[1];
#pragma unroll
    for (int i = 0; i < 7; ++i) {
        f2 xx = bc(h[i >> 1], i & 1);
        oA = pkfma(xx, wo[i * 2 + 0], oA);
        oB = pkfma(xx, wo[i * 2 + 1], oB);
    }
    o[0] = oA.x; o[1] = oA.y; o[2] = oB.x;
}

struct P12 { const void* p[12]; };
// seg order: 0:Wd1(7x9) 1:bd1(7) 2:Wdh(5x7x7) 3:bdh(5x7) 4:Wdo(3x7) 5:bdo(3)
//            6:Wf1(7x8) 7:bf1(7) 8:Wfh(5x7x7) 9:bfh(5x7) 10:Wfo(3x7) 11:bfo(3)

__global__ void prep(P12 ptrs, const unsigned int* __restrict__ tau_raw,
                     float* __restrict__ ws, int* __restrict__ flagp)
{
    __shared__ int sflag;
    int tid = threadIdx.x;
    if (tid < 64) {
        unsigned long long m = __ballot((tau_raw[tid] & 0x8000u) != 0u);
        if (tid == 0) { sflag = (m != 0ull) ? 1 : 0; *flagp = sflag; }
    }
    __syncthreads();
    const int f32m = sflag;

    auto rd = [&](int seg, int idx) -> float {
        if (f32m) return ((const float*)ptrs.p[seg])[idx];
        return bf2f(((const unsigned short*)ptrs.p[seg])[idx]);
    };
    auto ccf = [&](int c, int k) -> float {
        const float C1 = 1.0f / (0.25f * sqrtf(6.28f));
        float ii = (float)c * (1.0f / 29.0f);
        float jj = (float)k * 0.5f;
        float d = (ii - jj) * 4.0f;
        return C1 * expf(-0.5f * d * d);
    };

    // direct L1 packed [6][4][2] (columns 0..5 of Wd1)
    for (int i = tid; i < 48; i += 256) {
        int ii = i >> 3, p = (i >> 1) & 3, hl = i & 1, j = 2 * p + hl;
        ws[WD1P + i] = (j < 7) ? rd(0, j * 9 + ii) : 0.f;
    }
    // direct hidden packed [5][7][4][2]
    for (int i = tid; i < 280; i += 256) {
        int l = i / 56, r = i % 56;
        int ii = r >> 3, p = (r >> 1) & 3, hl = r & 1, j = 2 * p + hl;
        ws[WDHP + i] = (j < 7) ? rd(2, l * 49 + j * 7 + ii) : 0.f;
    }
    // direct hidden bias pairs [5][4][2]
    for (int i = tid; i < 40; i += 256) {
        int l = i / 8, p = (i >> 1) & 3, hl = i & 1, j = 2 * p + hl;
        ws[BDHP + i] = (j < 7) ? rd(3, l * 7 + j) : 0.f;
    }
    // direct out packed [7][2][2] x LOG2E
    for (int i = tid; i < 28; i += 256) {
        int ii = i >> 2, p = (i >> 1) & 1, hl = i & 1, k = 2 * p + hl;
        ws[WDOP + i] = (k < 3) ? rd(4, k * 7 + ii) * LOG2E : 0.f;
    }
    for (int i = tid; i < 4; i += 256)
        ws[BDOP + i] = (i < 3) ? rd(5, i) * LOG2E : 0.f;

    // beff_d[c][j] = bd1[j] + sum_k Wd1[j,6+k]*cc[c][k]
    for (int i = tid; i < 240; i += 256) {
        int c = i / 8, j = i % 8; float v = 0.f;
        if (j < 7) v = rd(1, j) + rd(0, j * 9 + 6) * ccf(c, 0)
                               + rd(0, j * 9 + 7) * ccf(c, 1)
                               + rd(0, j * 9 + 8) * ccf(c, 2);
        ws[BEFFD + i] = v;
    }
    // beff_f[c][j] = bf1[j] + sum_k Wf1[j,5+k]*cc[c][k]
    for (int i = tid; i < 240; i += 256) {
        int c = i / 8, j = i % 8; float v = 0.f;
        if (j < 7) v = rd(7, j) + rd(6, j * 8 + 5) * ccf(c, 0)
                               + rd(6, j * 8 + 6) * ccf(c, 1)
                               + rd(6, j * 8 + 7) * ccf(c, 2);
        ws[BEFFF + i] = v;
    }
    // diffuse L1 packed [8][4][2], natural-t order:
    // t0..t7 use Wf1 columns {0,1,3,4,4,2,4,4}
    for (int i = tid; i < 64; i += 256) {
        int ii = i >> 3, p = (i >> 1) & 3, hl = i & 1, j = 2 * p + hl;
        const int cols[8] = {0, 1, 3, 4, 4, 2, 4, 4};
        ws[WF1P + i] = (j < 7) ? rd(6, j * 8 + cols[ii]) : 0.f;
    }
    // diffuse hidden packed [5][7][4][2]
    for (int i = tid; i < 280; i += 256) {
        int l = i / 56, r = i % 56;
        int ii = r >> 3, p = (r >> 1) & 3, hl = r & 1, j = 2 * p + hl;
        ws[WFHP + i] = (j < 7) ? rd(8, l * 49 + j * 7 + ii) : 0.f;
    }
    // diffuse hidden bias pairs [5][4][2]
    for (int i = tid; i < 40; i += 256) {
        int l = i / 8, p = (i >> 1) & 3, hl = i & 1, j = 2 * p + hl;
        ws[BFHP + i] = (j < 7) ? rd(9, l * 7 + j) : 0.f;
    }
    // diffuse out packed [7][2][2] x LOG2E
    for (int i = tid; i < 28; i += 256) {
        int ii = i >> 2, p = (i >> 1) & 1, hl = i & 1, k = 2 * p + hl;
        ws[WFOP + i] = (k < 3) ? rd(10, k * 7 + ii) * LOG2E : 0.f;
    }
    for (int i = tid; i < 4; i += 256)
        ws[BFOP + i] = (i < 3) ? rd(11, i) * LOG2E : 0.f;
}

__global__ __launch_bounds__(256) void scatter_main(
    const void* __restrict__ tau_p,    // (B,C,8) bf16 or f32
    const void* __restrict__ mu_dir_p, // (B,1)
    const void* __restrict__ mu_dif_p, // (B,1)
    const float* __restrict__ ws,
    const int* __restrict__ flag,      // 1 = f32, 0 = bf16
    void* __restrict__ out_p)          // out: [BC | BC | 3BC | 3BC]
{
    __shared__ unsigned short sm[2048];  // 4 KiB output staging

    int tid = threadIdx.x;
    int eb0 = blockIdx.x * 256;
    int e = eb0 + tid;
    bool act = (e < BC);
    int eL = act ? e : (BC - 1);         // clamped index for loads (tail block)
    int b = eL / C_SZ;
    int c = eL - b * C_SZ;
    bool tail = (eb0 + 256 > BC);        // block-uniform

    int is_f32 = *flag;                  // grid-uniform

    float t0, t1, t2, t3, t4, t5, t6, t7, mu_d, mu_f;
    if (is_f32) {
        const float4* tf = (const float4*)tau_p;
        float4 a = tf[2 * eL];
        float4 bq = tf[2 * eL + 1];
        t0 = a.x; t1 = a.y; t2 = a.z; t3 = a.w;
        t4 = bq.x; t5 = bq.y; t6 = bq.z; t7 = bq.w;
        mu_d = ((const float*)mu_dir_p)[b];
        mu_f = ((const float*)mu_dif_p)[b];
    } else {
        uint4 t = ((const uint4*)tau_p)[eL];
        t0 = bf2f((unsigned short)(t.x & 0xffffu));
        t1 = bf2f((unsigned short)(t.x >> 16));
        t2 = bf2f((unsigned short)(t.y & 0xffffu));
        t3 = bf2f((unsigned short)(t.y >> 16));
        t4 = bf2f((unsigned short)(t.z & 0xffffu));
        t5 = bf2f((unsigned short)(t.z >> 16));
        t6 = bf2f((unsigned short)(t.w & 0xffffu));
        t7 = bf2f((unsigned short)(t.w >> 16));
        mu_d = bf2f(((const unsigned short*)mu_dir_p)[b]);
        mu_f = bf2f(((const unsigned short*)mu_dif_p)[b]);
    }

    float rcp_d = __builtin_amdgcn_rcpf(mu_d + EPSF);
    float rcp_f = __builtin_amdgcn_rcpf(mu_f + EPSF);

    float tau_total = ((t0 + t1) + (t2 + t3)) + ((t4 + t5) + (t6 + t7));
    float ttl = tau_total * LOG2E;
    float t_direct  = ex2(-ttl * rcp_d);
    float t_diffuse = ex2(-ttl * rcp_f);
    float s1 = (t3 + t4) + (t6 + t7);

    // per-c cc-folded L1 bias pairs (L1/L2-resident)
    f2 bed[4], bef[4];
    {
        const float4* q = (const float4*)(ws + BEFFD) + 2 * c;
        float4 qa = q[0], qb = q[1];
        bed[0] = f2{qa.x, qa.y}; bed[1] = f2{qa.z, qa.w};
        bed[2] = f2{qb.x, qb.y}; bed[3] = f2{qb.z, qb.w};
        const float4* r = (const float4*)(ws + BEFFF) + 2 * c;
        float4 ra = r[0], rb = r[1];
        bef[0] = f2{ra.x, ra.y}; bef[1] = f2{ra.z, ra.w};
        bef[2] = f2{rb.x, rb.y}; bef[3] = f2{rb.z, rb.w};
    }

    // direct MLP (packed f32): features [t0r, t1r, t5r, t2r, s1r, mu]
    f2 xd2[3] = { f2{t0 * rcp_d, t1 * rcp_d},
                  f2{t5 * rcp_d, t2 * rcp_d},
                  f2{s1 * rcp_d, mu_d} };
    float od[3];
    mlp_pk<6, WD1P, WDHP, BDHP, WDOP, BDOP>(ws, xd2, bed, od);

    // diffuse MLP (packed f32): natural t order
    f2 xf2[4] = { f2{t0, t1}, f2{t2, t3}, f2{t4, t5}, f2{t6, t7} };
    float of_[3];
    mlp_pk<8, WF1P, WFHP, BFHP, WFOP, BFOP>(ws, xf2, bef, of_);

    // softmax (logits pre-scaled by LOG2E)
    float md = fmaxf(fmaxf(od[0], od[1]), od[2]);
    float d0 = ex2(od[0] - md), d1 = ex2(od[1] - md), d2 = ex2(od[2] - md);
    float rd_ = __builtin_amdgcn_rcpf(d0 + d1 + d2);
    d0 *= rd_; d1 *= rd_; d2 *= rd_;

    float mf = fmaxf(fmaxf(of_[0], of_[1]), of_[2]);
    float f0 = ex2(of_[0] - mf), f1 = ex2(of_[1] - mf), f2v = ex2(of_[2] - mf);
    float rf = __builtin_amdgcn_rcpf(f0 + f1 + f2v);
    f0 *= rf; f1 *= rf; f2v *= rf;

    // ---------------- stores ----------------
    if (!is_f32 && !tail) {
        // LDS-staged coalesced path: 8 ds_write_u16 + 1 global_store_dwordx4
        unsigned int P1 = pk_bf16(t_direct, t_diffuse);
        unsigned int P2 = pk_bf16(d0, d1);
        unsigned int P3 = pk_bf16(d2, f0);
        unsigned int P4 = pk_bf16(f1, f2v);
        sm[tid]       = (unsigned short)P1;
        sm[256 + tid] = (unsigned short)(P1 >> 16);
        int db = 512 + 3 * tid;
        sm[db + 0] = (unsigned short)P2;
        sm[db + 1] = (unsigned short)(P2 >> 16);
        sm[db + 2] = (unsigned short)P3;
        int fb = 1280 + 3 * tid;
        sm[fb + 0] = (unsigned short)(P3 >> 16);
        sm[fb + 1] = (unsigned short)P4;
        sm[fb + 2] = (unsigned short)(P4 >> 16);
        __syncthreads();
        uint4 v = ((const uint4*)sm)[tid];
        unsigned int goff;  // byte offset into out
        if (tid < 32)        goff = 2u * eb0 + 16u * tid;
        else if (tid < 64)   goff = 2u * (BC + eb0) + 16u * (tid - 32);
        else if (tid < 160)  goff = 4u * BC + 6u * eb0 + 16u * (tid - 64);
        else                 goff = 10u * BC + 6u * eb0 + 16u * (tid - 160);
        *(uint4*)((char*)out_p + goff) = v;
    } else if (!is_f32) {
        // tail block: predicated scalar stores
        if (act) {
            unsigned short* out = (unsigned short*)out_p;
            int odb = 2 * BC + 3 * e;
            int ofb = 5 * BC + 3 * e;
            out[e]       = f2bf(t_direct);
            out[BC + e]  = f2bf(t_diffuse);
            out[odb + 0] = f2bf(d0);
            out[odb + 1] = f2bf(d1);
            out[odb + 2] = f2bf(d2);
            out[ofb + 0] = f2bf(f0);
            out[ofb + 1] = f2bf(f1);
            out[ofb + 2] = f2bf(f2v);
        }
    } else {
        if (act) {
            float* out = (float*)out_p;
            int odb = 2 * BC + 3 * e;
            int ofb = 5 * BC + 3 * e;
            out[e] = t_direct;
            out[BC + e] = t_diffuse;
            out[odb + 0] = d0; out[odb + 1] = d1; out[odb + 2] = d2;
            out[ofb + 0] = f0; out[ofb + 1] = f1; out[ofb + 2] = f2v;
        }
    }
}

extern "C" void kernel_launch(void* const* d_in, const int* in_sizes, int n_in,
                              void* d_out, int out_size, void* d_ws, size_t ws_size,
                              hipStream_t stream) {
    float* ws = (float*)d_ws;
    int* flag = (int*)((char*)d_ws + FLAG_BYTE_OFF);

    P12 p;
    for (int i = 0; i < 12; ++i) p.p[i] = d_in[3 + i];
    prep<<<1, 256, 0, stream>>>(p, (const unsigned int*)d_in[0], ws, flag);

    int nblk = (BC + 255) / 256;
    scatter_main<<<nblk, 256, 0, stream>>>(
        d_in[0], d_in[1], d_in[2], ws, flag, d_out);
}

// Round 3
// 839.120 us; speedup vs baseline: 1.0955x; 1.0007x over previous
//
#include <hip/hip_runtime.h>

// Scattering_v3_tau: B=500000, C=30, NCON=8, NCC=3, NH=7
// Round 5: latency-bound theory (VALUBusy~102% is a gfx94x-formula artifact,
// real busy ~50%; VGPR=20 shows minimal interleaving; occupancy 65%).
//  - 2 elements/thread: e and e+BC/2 (BC/2 % 30 == 0 -> same c, shared biases,
//    both tau streams coalesced)
//  - all 4 MLP instances (2 MLPs x 2 elems) fused into one interleaved loop:
//    16 independent pk_fma chains innermost; each weight s_load feeds 2 FMAs
//  - __launch_bounds__(256,4): give the scheduler VGPR headroom to interleave
//  - diffuse L1 down to 5 features [t0,t1,t5,t2,s1] (reference form, -8 pk/elem)
//  - keeps: packed f32 (bit-identical numerics), cc-folded biases, LOG2E folded,
//    LDS-staged coalesced bf16 stores, dtype-adaptive paths

#define B_SZ 500000
#define C_SZ 30
#define BC   (B_SZ * C_SZ)
#define HBC  (BC / 2)            /* 7,500,000 ; divisible by 30 */
#define EPSF 1e-7f
#define LOG2E 1.4426950408889634f

typedef float f2 __attribute__((ext_vector_type(2)));

// ws layout (float indices; all starts even -> 8B aligned; BEFF* 16B aligned)
enum {
    WD1P  = 0,     // [6][4][2]   direct L1 pairs, features [t0r,t1r,t5r,t2r,s1r,mu]
    WF1P  = 48,    // [6][4][2]   diffuse L1 pairs, features [t0,t1,t5,t2,s1,0]
    WDHP  = 96,    // [5][7][4][2]
    WFHP  = 376,   // [5][7][4][2]
    BDHP  = 656,   // [5][4][2]
    BFHP  = 696,   // [5][4][2]
    WDOP  = 736,   // [7][2][2]   (x LOG2E)
    BDOP  = 764,   // [2][2]      (x LOG2E)
    WFOP  = 768,   // [7][2][2]   (x LOG2E)
    BFOP  = 796,   // [2][2]      (x LOG2E)
    BEFFD = 800,   // [30][8]     cc-folded L1 biases, direct (slot7=0)
    BEFFF = 1040,  // [30][8]     diffuse
    WS_FLOATS = 1280
};
#define FLAG_BYTE_OFF 6144

__device__ __forceinline__ float bf2f(unsigned short u) {
    union { unsigned int i; float f; } v;
    v.i = ((unsigned int)u) << 16;
    return v.f;
}

__device__ __forceinline__ unsigned short f2bf(float f) {
    union { float f; unsigned int i; } v;
    v.f = f;
    unsigned int u = v.i;
    unsigned int r = u + 0x7fffu + ((u >> 16) & 1u);  // RNE
    return (unsigned short)(r >> 16);
}

__device__ __forceinline__ float ex2(float x) {
    float r;
    asm("v_exp_f32 %0, %1" : "=v"(r) : "v"(x));
    return r;
}

__device__ __forceinline__ unsigned int pk_bf16(float lo, float hi) {
    unsigned int r;
    asm("v_cvt_pk_bf16_f32 %0, %1, %2" : "=v"(r) : "v"(lo), "v"(hi));
    return r;
}

__device__ __forceinline__ f2 pkfma(f2 a, f2 b, f2 c) {
#if __has_builtin(__builtin_elementwise_fma)
    return __builtin_elementwise_fma(a, b, c);
#else
    f2 r; r.x = fmaf(a.x, b.x, c.x); r.y = fmaf(a.y, b.y, c.y); return r;
#endif
}

__device__ __forceinline__ f2 pkmax0(f2 a) {
    f2 z = {0.0f, 0.0f};
#if __has_builtin(__builtin_elementwise_max)
    return __builtin_elementwise_max(a, z);
#else
    f2 r; r.x = fmaxf(a.x, 0.f); r.y = fmaxf(a.y, 0.f); return r;
#endif
}

__device__ __forceinline__ f2 bc(f2 v, int hl) {
    return hl ? __builtin_shufflevector(v, v, 1, 1)
              : __builtin_shufflevector(v, v, 0, 0);
}

struct P12 { const void* p[12]; };
// seg order: 0:Wd1(7x9) 1:bd1(7) 2:Wdh(5x7x7) 3:bdh(5x7) 4:Wdo(3x7) 5:bdo(3)
//            6:Wf1(7x8) 7:bf1(7) 8:Wfh(5x7x7) 9:bfh(5x7) 10:Wfo(3x7) 11:bfo(3)

__global__ void prep(P12 ptrs, const unsigned int* __restrict__ tau_raw,
                     float* __restrict__ ws, int* __restrict__ flagp)
{
    __shared__ int sflag;
    int tid = threadIdx.x;
    if (tid < 64) {
        unsigned long long m = __ballot((tau_raw[tid] & 0x8000u) != 0u);
        if (tid == 0) { sflag = (m != 0ull) ? 1 : 0; *flagp = sflag; }
    }
    __syncthreads();
    const int f32m = sflag;

    auto rd = [&](int seg, int idx) -> float {
        if (f32m) return ((const float*)ptrs.p[seg])[idx];
        return bf2f(((const unsigned short*)ptrs.p[seg])[idx]);
    };
    auto ccf = [&](int c, int k) -> float {
        const float C1 = 1.0f / (0.25f * sqrtf(6.28f));
        float ii = (float)c * (1.0f / 29.0f);
        float jj = (float)k * 0.5f;
        float d = (ii - jj) * 4.0f;
        return C1 * expf(-0.5f * d * d);
    };

    // direct L1 packed [6][4][2]: feature i <-> Wd1 col i (i=0..5)
    for (int i = tid; i < 48; i += 256) {
        int ii = i >> 3, p = (i >> 1) & 3, hl = i & 1, j = 2 * p + hl;
        ws[WD1P + i] = (j < 7) ? rd(0, j * 9 + ii) : 0.f;
    }
    // diffuse L1 packed [6][4][2]: feature i <-> Wf1 col i (i=0..4), slot5 = 0
    for (int i = tid; i < 48; i += 256) {
        int ii = i >> 3, p = (i >> 1) & 3, hl = i & 1, j = 2 * p + hl;
        ws[WF1P + i] = (j < 7 && ii < 5) ? rd(6, j * 8 + ii) : 0.f;
    }
    // hidden packed [5][7][4][2]
    for (int i = tid; i < 280; i += 256) {
        int l = i / 56, r = i % 56;
        int ii = r >> 3, p = (r >> 1) & 3, hl = r & 1, j = 2 * p + hl;
        ws[WDHP + i] = (j < 7) ? rd(2, l * 49 + j * 7 + ii) : 0.f;
        ws[WFHP + i] = (j < 7) ? rd(8, l * 49 + j * 7 + ii) : 0.f;
    }
    // hidden bias pairs [5][4][2]
    for (int i = tid; i < 40; i += 256) {
        int l = i / 8, p = (i >> 1) & 3, hl = i & 1, j = 2 * p + hl;
        ws[BDHP + i] = (j < 7) ? rd(3, l * 7 + j) : 0.f;
        ws[BFHP + i] = (j < 7) ? rd(9, l * 7 + j) : 0.f;
    }
    // out packed [7][2][2] x LOG2E
    for (int i = tid; i < 28; i += 256) {
        int ii = i >> 2, p = (i >> 1) & 1, hl = i & 1, k = 2 * p + hl;
        ws[WDOP + i] = (k < 3) ? rd(4, k * 7 + ii) * LOG2E : 0.f;
        ws[WFOP + i] = (k < 3) ? rd(10, k * 7 + ii) * LOG2E : 0.f;
    }
    for (int i = tid; i < 4; i += 256) {
        ws[BDOP + i] = (i < 3) ? rd(5, i) * LOG2E : 0.f;
        ws[BFOP + i] = (i < 3) ? rd(11, i) * LOG2E : 0.f;
    }
    // beff_d[c][j] = bd1[j] + sum_k Wd1[j,6+k]*cc[c][k]
    for (int i = tid; i < 240; i += 256) {
        int c = i / 8, j = i % 8; float v = 0.f;
        if (j < 7) v = rd(1, j) + rd(0, j * 9 + 6) * ccf(c, 0)
                               + rd(0, j * 9 + 7) * ccf(c, 1)
                               + rd(0, j * 9 + 8) * ccf(c, 2);
        ws[BEFFD + i] = v;
    }
    // beff_f[c][j] = bf1[j] + sum_k Wf1[j,5+k]*cc[c][k]
    for (int i = tid; i < 240; i += 256) {
        int c = i / 8, j = i % 8; float v = 0.f;
        if (j < 7) v = rd(7, j) + rd(6, j * 8 + 5) * ccf(c, 0)
                               + rd(6, j * 8 + 6) * ccf(c, 1)
                               + rd(6, j * 8 + 7) * ccf(c, 2);
        ws[BEFFF + i] = v;
    }
}

__global__ __launch_bounds__(256, 4) void scatter_main(
    const void* __restrict__ tau_p,    // (B,C,8) bf16 or f32
    const void* __restrict__ mu_dir_p, // (B,1)
    const void* __restrict__ mu_dif_p, // (B,1)
    const float* __restrict__ ws,
    const int* __restrict__ flag,      // 1 = f32, 0 = bf16
    void* __restrict__ out_p)          // out: [BC | BC | 3BC | 3BC]
{
    __shared__ unsigned short sm[2][2048];  // 8 KiB output staging (2 halves)

    int tid = threadIdx.x;
    int eb0 = blockIdx.x * 256;
    int e0 = eb0 + tid;                  // [0, HBC)
    bool act = (e0 < HBC);
    int eL = act ? e0 : (HBC - 1);
    int b0 = eL / C_SZ;
    int c  = eL - b0 * C_SZ;
    int b1 = b0 + (HBC / C_SZ);          // +250000
    bool tail = (eb0 + 256 > HBC);       // block-uniform

    int is_f32 = *flag;                  // grid-uniform

    // ---------------- loads, both halves ----------------
    float T[2][8], MUD[2], MUF[2];
    if (is_f32) {
        const float4* tf = (const float4*)tau_p;
#pragma unroll
        for (int h = 0; h < 2; ++h) {
            int ee = eL + h * HBC;
            float4 a = tf[2 * ee], bq = tf[2 * ee + 1];
            T[h][0] = a.x;  T[h][1] = a.y;  T[h][2] = a.z;  T[h][3] = a.w;
            T[h][4] = bq.x; T[h][5] = bq.y; T[h][6] = bq.z; T[h][7] = bq.w;
        }
        MUD[0] = ((const float*)mu_dir_p)[b0];
        MUD[1] = ((const float*)mu_dir_p)[b1];
        MUF[0] = ((const float*)mu_dif_p)[b0];
        MUF[1] = ((const float*)mu_dif_p)[b1];
    } else {
        const uint4* tu = (const uint4*)tau_p;
#pragma unroll
        for (int h = 0; h < 2; ++h) {
            uint4 t = tu[eL + h * HBC];
            T[h][0] = bf2f((unsigned short)(t.x & 0xffffu));
            T[h][1] = bf2f((unsigned short)(t.x >> 16));
            T[h][2] = bf2f((unsigned short)(t.y & 0xffffu));
            T[h][3] = bf2f((unsigned short)(t.y >> 16));
            T[h][4] = bf2f((unsigned short)(t.z & 0xffffu));
            T[h][5] = bf2f((unsigned short)(t.z >> 16));
            T[h][6] = bf2f((unsigned short)(t.w & 0xffffu));
            T[h][7] = bf2f((unsigned short)(t.w >> 16));
        }
        MUD[0] = bf2f(((const unsigned short*)mu_dir_p)[b0]);
        MUD[1] = bf2f(((const unsigned short*)mu_dir_p)[b1]);
        MUF[0] = bf2f(((const unsigned short*)mu_dif_p)[b0]);
        MUF[1] = bf2f(((const unsigned short*)mu_dif_p)[b1]);
    }

    // shared per-c cc-folded L1 bias pairs
    f2 bed[4], bef[4];
    {
        const float4* q = (const float4*)(ws + BEFFD) + 2 * c;
        float4 qa = q[0], qb = q[1];
        bed[0] = f2{qa.x, qa.y}; bed[1] = f2{qa.z, qa.w};
        bed[2] = f2{qb.x, qb.y}; bed[3] = f2{qb.z, qb.w};
        const float4* r = (const float4*)(ws + BEFFF) + 2 * c;
        float4 ra = r[0], rb = r[1];
        bef[0] = f2{ra.x, ra.y}; bef[1] = f2{ra.z, ra.w};
        bef[2] = f2{rb.x, rb.y}; bef[3] = f2{rb.z, rb.w};
    }

    // ---------------- per-half prologue ----------------
    float tdir[2], tdif[2];
    f2 xd[2][3], xf[2][3];
#pragma unroll
    for (int h = 0; h < 2; ++h) {
        float rcp_d = __builtin_amdgcn_rcpf(MUD[h] + EPSF);
        float rcp_f = __builtin_amdgcn_rcpf(MUF[h] + EPSF);
        float tt = ((T[h][0] + T[h][1]) + (T[h][2] + T[h][3]))
                 + ((T[h][4] + T[h][5]) + (T[h][6] + T[h][7]));
        float ttl = tt * LOG2E;
        tdir[h] = ex2(-ttl * rcp_d);
        tdif[h] = ex2(-ttl * rcp_f);
        float s1 = (T[h][3] + T[h][4]) + (T[h][6] + T[h][7]);
        xd[h][0] = f2{T[h][0] * rcp_d, T[h][1] * rcp_d};
        xd[h][1] = f2{T[h][5] * rcp_d, T[h][2] * rcp_d};
        xd[h][2] = f2{s1 * rcp_d, MUD[h]};
        xf[h][0] = f2{T[h][0], T[h][1]};
        xf[h][1] = f2{T[h][5], T[h][2]};
        xf[h][2] = f2{s1, 0.0f};
    }

    // ---------------- fused 4-instance MLP (16 independent chains) ----------------
    f2 hD[2][4], hF[2][4];
#pragma unroll
    for (int p = 0; p < 4; ++p) {
        hD[0][p] = bed[p]; hD[1][p] = bed[p];
        hF[0][p] = bef[p]; hF[1][p] = bef[p];
    }
    {
        const f2* w1d = (const f2*)(ws + WD1P);
        const f2* w1f = (const f2*)(ws + WF1P);
#pragma unroll
        for (int i = 0; i < 6; ++i) {
            f2 a0 = bc(xd[0][i >> 1], i & 1), a1 = bc(xd[1][i >> 1], i & 1);
            f2 b0v = bc(xf[0][i >> 1], i & 1), b1v = bc(xf[1][i >> 1], i & 1);
#pragma unroll
            for (int p = 0; p < 4; ++p) {
                f2 wd = w1d[i * 4 + p], wf = w1f[i * 4 + p];
                hD[0][p] = pkfma(a0, wd, hD[0][p]);
                hD[1][p] = pkfma(a1, wd, hD[1][p]);
                hF[0][p] = pkfma(b0v, wf, hF[0][p]);
                hF[1][p] = pkfma(b1v, wf, hF[1][p]);
            }
        }
#pragma unroll
        for (int p = 0; p < 4; ++p) {
            hD[0][p] = pkmax0(hD[0][p]); hD[1][p] = pkmax0(hD[1][p]);
            hF[0][p] = pkmax0(hF[0][p]); hF[1][p] = pkmax0(hF[1][p]);
        }
    }
    {
        const f2* whd = (const f2*)(ws + WDHP);
        const f2* whf = (const f2*)(ws + WFHP);
        const f2* bhd = (const f2*)(ws + BDHP);
        const f2* bhf = (const f2*)(ws + BFHP);
#pragma unroll
        for (int l = 0; l < 5; ++l) {
            f2 nD[2][4], nF[2][4];
#pragma unroll
            for (int p = 0; p < 4; ++p) {
                f2 bd = bhd[l * 4 + p], bfv = bhf[l * 4 + p];
                nD[0][p] = bd;  nD[1][p] = bd;
                nF[0][p] = bfv; nF[1][p] = bfv;
            }
#pragma unroll
            for (int i = 0; i < 7; ++i) {
                f2 a0 = bc(hD[0][i >> 1], i & 1), a1 = bc(hD[1][i >> 1], i & 1);
                f2 c0 = bc(hF[0][i >> 1], i & 1), c1 = bc(hF[1][i >> 1], i & 1);
#pragma unroll
                for (int p = 0; p < 4; ++p) {
                    f2 wd = whd[(l * 7 + i) * 4 + p], wf = whf[(l * 7 + i) * 4 + p];
                    nD[0][p] = pkfma(a0, wd, nD[0][p]);
                    nD[1][p] = pkfma(a1, wd, nD[1][p]);
                    nF[0][p] = pkfma(c0, wf, nF[0][p]);
                    nF[1][p] = pkfma(c1, wf, nF[1][p]);
                }
            }
#pragma unroll
            for (int p = 0; p < 4; ++p) {
                hD[0][p] = pkmax0(nD[0][p]); hD[1][p] = pkmax0(nD[1][p]);
                hF[0][p] = pkmax0(nF[0][p]); hF[1][p] = pkmax0(nF[1][p]);
            }
        }
    }
    float od[2][3], of_[2][3];
    {
        const f2* wod = (const f2*)(ws + WDOP);
        const f2* wof = (const f2*)(ws + WFOP);
        const f2* bod = (const f2*)(ws + BDOP);
        const f2* bof = (const f2*)(ws + BFOP);
        f2 oDa[2] = {bod[0], bod[0]}, oDb[2] = {bod[1], bod[1]};
        f2 oFa[2] = {bof[0], bof[0]}, oFb[2] = {bof[1], bof[1]};
#pragma unroll
        for (int i = 0; i < 7; ++i) {
            f2 w0 = wod[i * 2 + 0], w1 = wod[i * 2 + 1];
            f2 v0 = wof[i * 2 + 0], v1 = wof[i * 2 + 1];
#pragma unroll
            for (int h = 0; h < 2; ++h) {
                f2 ad = bc(hD[h][i >> 1], i & 1);
                f2 af = bc(hF[h][i >> 1], i & 1);
                oDa[h] = pkfma(ad, w0, oDa[h]);
                oDb[h] = pkfma(ad, w1, oDb[h]);
                oFa[h] = pkfma(af, v0, oFa[h]);
                oFb[h] = pkfma(af, v1, oFb[h]);
            }
        }
#pragma unroll
        for (int h = 0; h < 2; ++h) {
            od[h][0] = oDa[h].x; od[h][1] = oDa[h].y; od[h][2] = oDb[h].x;
            of_[h][0] = oFa[h].x; of_[h][1] = oFa[h].y; of_[h][2] = oFb[h].x;
        }
    }

    // ---------------- softmax (logits pre-scaled by LOG2E) ----------------
    float D0[2], D1[2], D2[2], F0[2], F1[2], F2[2];
#pragma unroll
    for (int h = 0; h < 2; ++h) {
        float md = fmaxf(fmaxf(od[h][0], od[h][1]), od[h][2]);
        float d0 = ex2(od[h][0] - md), d1 = ex2(od[h][1] - md), d2 = ex2(od[h][2] - md);
        float rdd = __builtin_amdgcn_rcpf(d0 + d1 + d2);
        D0[h] = d0 * rdd; D1[h] = d1 * rdd; D2[h] = d2 * rdd;
        float mf = fmaxf(fmaxf(of_[h][0], of_[h][1]), of_[h][2]);
        float f0 = ex2(of_[h][0] - mf), f1 = ex2(of_[h][1] - mf), f2v = ex2(of_[h][2] - mf);
        float rff = __builtin_amdgcn_rcpf(f0 + f1 + f2v);
        F0[h] = f0 * rff; F1[h] = f1 * rff; F2[h] = f2v * rff;
    }

    // ---------------- stores ----------------
    if (!is_f32 && !tail) {
        // LDS-staged coalesced path, both halves
#pragma unroll
        for (int h = 0; h < 2; ++h) {
            unsigned int P1 = pk_bf16(tdir[h], tdif[h]);
            unsigned int P2 = pk_bf16(D0[h], D1[h]);
            unsigned int P3 = pk_bf16(D2[h], F0[h]);
            unsigned int P4 = pk_bf16(F1[h], F2[h]);
            sm[h][tid]       = (unsigned short)P1;
            sm[h][256 + tid] = (unsigned short)(P1 >> 16);
            int db = 512 + 3 * tid;
            sm[h][db + 0] = (unsigned short)P2;
            sm[h][db + 1] = (unsigned short)(P2 >> 16);
            sm[h][db + 2] = (unsigned short)P3;
            int fb = 1280 + 3 * tid;
            sm[h][fb + 0] = (unsigned short)(P3 >> 16);
            sm[h][fb + 1] = (unsigned short)P4;
            sm[h][fb + 2] = (unsigned short)(P4 >> 16);
        }
        __syncthreads();
#pragma unroll
        for (int h = 0; h < 2; ++h) {
            uint4 v = ((const uint4*)sm[h])[tid];
            unsigned int E = (h ? (unsigned int)HBC : 0u) + (unsigned int)eb0;
            unsigned int goff;
            if (tid < 32)        goff = 2u * E + 16u * tid;
            else if (tid < 64)   goff = 2u * ((unsigned int)BC + E) + 16u * (tid - 32);
            else if (tid < 160)  goff = 4u * (unsigned int)BC + 6u * E + 16u * (tid - 64);
            else                 goff = 10u * (unsigned int)BC + 6u * E + 16u * (tid - 160);
            *(uint4*)((char*)out_p + goff) = v;
        }
    } else if (!is_f32) {
        if (act) {
            unsigned short* out = (unsigned short*)out_p;
#pragma unroll
            for (int h = 0; h < 2; ++h) {
                int e = e0 + h * HBC;
                int odb = 2 * BC + 3 * e;
                int ofb = 5 * BC + 3 * e;
                out[e]       = f2bf(tdir[h]);
                out[BC + e]  = f2bf(tdif[h]);
                out[odb + 0] = f2bf(D0[h]);
                out[odb + 1] = f2bf(D1[h]);
                out[odb + 2] = f2bf(D2[h]);
                out[ofb + 0] = f2bf(F0[h]);
                out[ofb + 1] = f2bf(F1[h]);
                out[ofb + 2] = f2bf(F2[h]);
            }
        }
    } else {
        if (act) {
            float* out = (float*)out_p;
#pragma unroll
            for (int h = 0; h < 2; ++h) {
                int e = e0 + h * HBC;
                int odb = 2 * BC + 3 * e;
                int ofb = 5 * BC + 3 * e;
                out[e] = tdir[h];
                out[BC + e] = tdif[h];
                out[odb + 0] = D0[h]; out[odb + 1] = D1[h]; out[odb + 2] = D2[h];
                out[ofb + 0] = F0[h]; out[ofb + 1] = F1[h]; out[ofb + 2] = F2[h];
            }
        }
    }
}

extern "C" void kernel_launch(void* const* d_in, const int* in_sizes, int n_in,
                              void* d_out, int out_size, void* d_ws, size_t ws_size,
                              hipStream_t stream) {
    float* ws = (float*)d_ws;
    int* flag = (int*)((char*)d_ws + FLAG_BYTE_OFF);

    P12 p;
    for (int i = 0; i < 12; ++i) p.p[i] = d_in[3 + i];
    prep<<<1, 256, 0, stream>>>(p, (const unsigned int*)d_in[0], ws, flag);

    int nblk = (HBC + 255) / 256;
    scatter_main<<<nblk, 256, 0, stream>>>(
        d_in[0], d_in[1], d_in[2], ws, flag, d_out);
}